// Round 1
// baseline (517.094 us; speedup 1.0000x reference)
//
#include <hip/hip_runtime.h>

#define N_NODES 100000
#define N_EDGES 600000
#define DIM 128

// ---------------- CSR build ----------------

__global__ void hist_k(const int* __restrict__ dst, int* __restrict__ deg) {
  int e = blockIdx.x * blockDim.x + threadIdx.x;
  if (e < N_EDGES) atomicAdd(&deg[dst[e]], 1);
}

__global__ void scan_k(const int* __restrict__ deg, int* __restrict__ rowptr,
                       int* __restrict__ head) {
  __shared__ int wsum[16];
  __shared__ int carry_s;
  const int t = threadIdx.x, lane = t & 63, w = t >> 6;
  if (t == 0) carry_s = 0;
  __syncthreads();
  for (int base = 0; base < N_NODES; base += 1024) {
    int i = base + t;
    int v = (i < N_NODES) ? deg[i] : 0;
    int s = v;
#pragma unroll
    for (int off = 1; off < 64; off <<= 1) {
      int u = __shfl_up(s, off);
      if (lane >= off) s += u;
    }
    if (lane == 63) wsum[w] = s;
    __syncthreads();
    if (t < 16) {
      int ws = wsum[t];
#pragma unroll
      for (int off = 1; off < 16; off <<= 1) {
        int u = __shfl_up(ws, off);
        if (lane >= off) ws += u;
      }
      wsum[t] = ws;  // inclusive scan of wave sums
    }
    __syncthreads();
    int excl = carry_s + (w ? wsum[w - 1] : 0) + s - v;
    if (i < N_NODES) {
      rowptr[i] = excl;
      head[i] = excl;
    }
    __syncthreads();
    if (t == 0) carry_s += wsum[15];
    __syncthreads();
  }
  if (t == 0) rowptr[N_NODES] = carry_s;  // == N_EDGES
}

__global__ void fill_k(const int* __restrict__ src, const int* __restrict__ dst,
                       int* __restrict__ head, int* __restrict__ col) {
  int e = blockIdx.x * blockDim.x + threadIdx.x;
  if (e < N_EDGES) {
    int p = atomicAdd(&head[dst[e]], 1);
    col[p] = src[e];
  }
}

// ---------------- scatter-mean via CSR gather ----------------
// 8 nodes per 256-thread block; 32 lanes x float4 per node (512B coalesced per neighbor).

__global__ __launch_bounds__(256) void aggregate_k(
    const float* __restrict__ h, const int* __restrict__ rowptr,
    const int* __restrict__ col, float* __restrict__ mean) {
  const int t = threadIdx.x;
  const int node = blockIdx.x * 8 + (t >> 5);
  const int c = (t & 31) << 2;
  const int beg = rowptr[node], end = rowptr[node + 1];
  float4 acc = make_float4(0.f, 0.f, 0.f, 0.f);
  for (int i = beg; i < end; ++i) {
    const float4 v =
        *reinterpret_cast<const float4*>(h + (size_t)col[i] * DIM + c);
    acc.x += v.x;
    acc.y += v.y;
    acc.z += v.z;
    acc.w += v.w;
  }
  const int d = end - beg;
  const float inv = 1.0f / (float)(d > 1 ? d : 1);
  acc.x *= inv;
  acc.y *= inv;
  acc.z *= inv;
  acc.w *= inv;
  *reinterpret_cast<float4*>(mean + (size_t)node * DIM + c) = acc;
}

// ---------------- fused linear: out = relu(A@Wl + b + H@Wr) ----------------
// 32 nodes / block, 256 threads, 4x4 register tile per thread, k unrolled by 4.

__global__ __launch_bounds__(256) void linear_k(
    const float* __restrict__ A, const float* __restrict__ H,
    const float* __restrict__ Wl, const float* __restrict__ Wr,
    const float* __restrict__ bl, float* __restrict__ out) {
  __shared__ float sA[32][DIM];
  __shared__ float sH[32][DIM];
  const int t = threadIdx.x;
  const int nb = blockIdx.x * 32;
  for (int idx = t; idx < 32 * 32; idx += 256) {
    const int r = idx >> 5, c = (idx & 31) << 2;
    *reinterpret_cast<float4*>(&sA[r][c]) =
        *reinterpret_cast<const float4*>(A + (size_t)(nb + r) * DIM + c);
    *reinterpret_cast<float4*>(&sH[r][c]) =
        *reinterpret_cast<const float4*>(H + (size_t)(nb + r) * DIM + c);
  }
  __syncthreads();
  const int tx = t & 31, ty = t >> 5;
  const int c0 = tx << 2;
  float acc[4][4] = {};
  for (int k = 0; k < DIM; k += 4) {
    float4 wl[4], wr[4];
#pragma unroll
    for (int kk = 0; kk < 4; ++kk) {
      wl[kk] = *reinterpret_cast<const float4*>(Wl + (size_t)(k + kk) * DIM + c0);
      wr[kk] = *reinterpret_cast<const float4*>(Wr + (size_t)(k + kk) * DIM + c0);
    }
#pragma unroll
    for (int i = 0; i < 4; ++i) {
      const int r = ty * 4 + i;
      float4 a = *reinterpret_cast<const float4*>(&sA[r][k]);
      float4 h4 = *reinterpret_cast<const float4*>(&sH[r][k]);
      const float* ap = (const float*)&a;
      const float* hp = (const float*)&h4;
#pragma unroll
      for (int kk = 0; kk < 4; ++kk) {
        const float* wlp = (const float*)&wl[kk];
        const float* wrp = (const float*)&wr[kk];
#pragma unroll
        for (int j = 0; j < 4; ++j)
          acc[i][j] += ap[kk] * wlp[j] + hp[kk] * wrp[j];
      }
    }
  }
  const float4 bv = *reinterpret_cast<const float4*>(bl + c0);
  const float* bp = (const float*)&bv;
#pragma unroll
  for (int i = 0; i < 4; ++i) {
    float4 o;
    float* op = (float*)&o;
#pragma unroll
    for (int j = 0; j < 4; ++j) {
      const float v = acc[i][j] + bp[j];
      op[j] = v > 0.f ? v : 0.f;
    }
    *reinterpret_cast<float4*>(out + (size_t)(nb + ty * 4 + i) * DIM + c0) = o;
  }
}

// ---------------- launcher ----------------

extern "C" void kernel_launch(void* const* d_in, const int* in_sizes, int n_in,
                              void* d_out, int out_size, void* d_ws,
                              size_t ws_size, hipStream_t stream) {
  const float* x = (const float*)d_in[0];
  const int* ei = (const int*)d_in[1];
  const float* Wl0 = (const float*)d_in[2];
  const float* bl0 = (const float*)d_in[3];
  const float* Wr0 = (const float*)d_in[4];
  const float* Wl1 = (const float*)d_in[5];
  const float* bl1 = (const float*)d_in[6];
  const float* Wr1 = (const float*)d_in[7];
  float* out = (float*)d_out;
  const int* src = ei;            // edge_index[0]
  const int* dst = ei + N_EDGES;  // edge_index[1]

  char* p = (char*)d_ws;
  auto alloc = [&](size_t bytes) {
    char* q = p;
    p += (bytes + 255) & ~(size_t)255;
    return q;
  };
  int* deg = (int*)alloc((size_t)N_NODES * 4);
  int* rowptr = (int*)alloc((size_t)(N_NODES + 1) * 4);
  int* head = (int*)alloc((size_t)N_NODES * 4);
  int* col = (int*)alloc((size_t)N_EDGES * 4);
  float* mean = (float*)alloc((size_t)N_NODES * DIM * 4);
  float* h1 = (float*)alloc((size_t)N_NODES * DIM * 4);

  hipMemsetAsync(deg, 0, (size_t)N_NODES * 4, stream);
  hist_k<<<(N_EDGES + 255) / 256, 256, 0, stream>>>(dst, deg);
  scan_k<<<1, 1024, 0, stream>>>(deg, rowptr, head);
  fill_k<<<(N_EDGES + 255) / 256, 256, 0, stream>>>(src, dst, head, col);

  // layer 0
  aggregate_k<<<N_NODES / 8, 256, 0, stream>>>(x, rowptr, col, mean);
  linear_k<<<N_NODES / 32, 256, 0, stream>>>(mean, x, Wl0, Wr0, bl0, h1);
  // layer 1
  aggregate_k<<<N_NODES / 8, 256, 0, stream>>>(h1, rowptr, col, mean);
  linear_k<<<N_NODES / 32, 256, 0, stream>>>(mean, h1, Wl1, Wr1, bl1, out);
}

// Round 2
// 310.546 us; speedup vs baseline: 1.6651x; 1.6651x over previous
//
#include <hip/hip_runtime.h>

#define N_NODES 100000
#define N_EDGES 600000
#define DIM 128

typedef __attribute__((ext_vector_type(8))) short bf16x8;
typedef __attribute__((ext_vector_type(4))) float f32x4;

__device__ inline unsigned short f32_to_bf16_rn(float f) {
  unsigned int u = __builtin_bit_cast(unsigned int, f);
  unsigned int r = (u + 0x7FFFu + ((u >> 16) & 1u)) >> 16;
  return (unsigned short)r;
}
__device__ inline float bf16_to_f32(unsigned short h) {
  return __builtin_bit_cast(float, (unsigned int)h << 16);
}

// ---------------- split f32 -> (hi, lo) bf16 planes ----------------
__global__ __launch_bounds__(256) void split_k(const float* __restrict__ in,
                                               unsigned short* __restrict__ hi,
                                               unsigned short* __restrict__ lo) {
  const int i = blockIdx.x * 256 + threadIdx.x;  // one float4 per thread
  const float4 v = reinterpret_cast<const float4*>(in)[i];
  const float f[4] = {v.x, v.y, v.z, v.w};
  unsigned short h[4], l[4];
#pragma unroll
  for (int j = 0; j < 4; ++j) {
    h[j] = f32_to_bf16_rn(f[j]);
    l[j] = f32_to_bf16_rn(f[j] - bf16_to_f32(h[j]));
  }
  uint2 hp, lp;
  hp.x = (unsigned)h[0] | ((unsigned)h[1] << 16);
  hp.y = (unsigned)h[2] | ((unsigned)h[3] << 16);
  lp.x = (unsigned)l[0] | ((unsigned)l[1] << 16);
  lp.y = (unsigned)l[2] | ((unsigned)l[3] << 16);
  reinterpret_cast<uint2*>(hi)[i] = hp;
  reinterpret_cast<uint2*>(lo)[i] = lp;
}

// ---------------- pack weights into MFMA fragment order ----------------
// B'' rows 0-127: Wl_hi, 128-255: Wl_lo, 256-383: Wr_hi, 384-511: Wr_lo
// packed[(((kt*8+nt)*64)+lane)*8 + j] = B''[kt*32 + (lane>>4)*8 + j][nt*16 + (lane&15)]
__global__ __launch_bounds__(256) void pack_w_k(const float* __restrict__ Wl,
                                                const float* __restrict__ Wr,
                                                unsigned short* __restrict__ packed) {
  const int idx = blockIdx.x * 256 + threadIdx.x;  // 0..65535
  const int j = idx & 7;
  const int l = (idx >> 3) & 63;
  const int nt = (idx >> 9) & 7;
  const int kt = idx >> 12;
  const int kk = kt * 32 + ((l >> 4) << 3) + j;
  const int n = nt * 16 + (l & 15);
  const int p = kk >> 7;            // 0:Wl_hi 1:Wl_lo 2:Wr_hi 3:Wr_lo
  const int k = kk & 127;
  const float w = ((p < 2) ? Wl : Wr)[k * 128 + n];
  const unsigned short h = f32_to_bf16_rn(w);
  const unsigned short out =
      (p & 1) ? f32_to_bf16_rn(w - bf16_to_f32(h)) : h;
  packed[idx] = out;
}

// ---------------- CSR build ----------------
__global__ void hist_k(const int* __restrict__ dst, int* __restrict__ deg) {
  int e = blockIdx.x * blockDim.x + threadIdx.x;
  if (e < N_EDGES) atomicAdd(&deg[dst[e]], 1);
}

__global__ __launch_bounds__(1024) void scan1_k(const int* __restrict__ deg,
                                                int* __restrict__ incl,
                                                int* __restrict__ bsum) {
  __shared__ int wsum[16];
  const int t = threadIdx.x, lane = t & 63, w = t >> 6;
  const int gi = blockIdx.x * 1024 + t;
  int v = (gi < N_NODES) ? deg[gi] : 0;
  int s = v;
#pragma unroll
  for (int off = 1; off < 64; off <<= 1) {
    int u = __shfl_up(s, off);
    if (lane >= off) s += u;
  }
  if (lane == 63) wsum[w] = s;
  __syncthreads();
  if (t < 16) {
    int ws = wsum[t];
#pragma unroll
    for (int off = 1; off < 16; off <<= 1) {
      int u = __shfl_up(ws, off);
      if (t >= off) ws += u;
    }
    wsum[t] = ws;
  }
  __syncthreads();
  const int val = s + (w ? wsum[w - 1] : 0);
  if (gi < N_NODES) incl[gi] = val;
  if (t == 1023) bsum[blockIdx.x] = val;
}

__global__ void scan2_k(const int* __restrict__ bsum, int* __restrict__ boffs,
                        int nb) {
  __shared__ int w0;
  const int t = threadIdx.x;  // 128 threads
  int v = (t < nb) ? bsum[t] : 0;
  int s = v;
#pragma unroll
  for (int off = 1; off < 64; off <<= 1) {
    int u = __shfl_up(s, off);
    if ((t & 63) >= off) s += u;
  }
  if (t == 63) w0 = s;
  __syncthreads();
  const int excl = s - v + ((t >> 6) ? w0 : 0);
  if (t < nb) boffs[t] = excl;
}

__global__ __launch_bounds__(1024) void scan3_k(const int* __restrict__ deg,
                                                const int* __restrict__ incl,
                                                const int* __restrict__ boffs,
                                                int* __restrict__ rowptr,
                                                int* __restrict__ head) {
  const int gi = blockIdx.x * 1024 + threadIdx.x;
  if (gi < N_NODES) {
    const int e = incl[gi] - deg[gi] + boffs[blockIdx.x];
    rowptr[gi] = e;
    head[gi] = e;
  }
  if (gi == 0) rowptr[N_NODES] = N_EDGES;
}

__global__ void fill_k(const int* __restrict__ src, const int* __restrict__ dst,
                       int* __restrict__ head, int* __restrict__ col) {
  int e = blockIdx.x * blockDim.x + threadIdx.x;
  if (e < N_EDGES) {
    int p = atomicAdd(&head[dst[e]], 1);
    col[p] = src[e];
  }
}

// ---------------- mean aggregation over split planes ----------------
// 8 nodes / 256-thread block; 32 lanes per node: lanes 0-15 hi plane, 16-31 lo.
__global__ __launch_bounds__(256) void agg_k(
    const unsigned short* __restrict__ hi, const unsigned short* __restrict__ lo,
    const int* __restrict__ rowptr, const int* __restrict__ col,
    unsigned short* __restrict__ mhi, unsigned short* __restrict__ mlo) {
  const int t = threadIdx.x;
  const int node = blockIdx.x * 8 + (t >> 5);
  const int c = t & 31;
  const unsigned short* plane = (c & 16) ? lo : hi;
  const int off = (c & 15) << 3;  // 8 bf16 per lane
  const int beg = rowptr[node], end = rowptr[node + 1];
  float acc[8] = {};
  for (int i = beg; i < end; ++i) {
    const uint4 v = *reinterpret_cast<const uint4*>(
        plane + (size_t)col[i] * DIM + off);
    const unsigned int u[4] = {v.x, v.y, v.z, v.w};
#pragma unroll
    for (int q = 0; q < 4; ++q) {
      acc[2 * q] += __builtin_bit_cast(float, u[q] << 16);
      acc[2 * q + 1] += __builtin_bit_cast(float, u[q] & 0xFFFF0000u);
    }
  }
  const int d = end - beg;
  const float inv = 1.0f / (float)(d > 1 ? d : 1);
  unsigned short outv[8];
#pragma unroll
  for (int j = 0; j < 8; ++j) {
    const float tot = acc[j] + __shfl_xor(acc[j], 16);
    const float m = tot * inv;
    const unsigned short h = f32_to_bf16_rn(m);
    const unsigned short lw = f32_to_bf16_rn(m - bf16_to_f32(h));
    outv[j] = (c & 16) ? lw : h;
  }
  uint4 pk;
  pk.x = (unsigned)outv[0] | ((unsigned)outv[1] << 16);
  pk.y = (unsigned)outv[2] | ((unsigned)outv[3] << 16);
  pk.z = (unsigned)outv[4] | ((unsigned)outv[5] << 16);
  pk.w = (unsigned)outv[6] | ((unsigned)outv[7] << 16);
  unsigned short* op = (c & 16) ? mlo : mhi;
  *reinterpret_cast<uint4*>(op + (size_t)node * DIM + off) = pk;
}

// ---------------- MFMA GEMM: out = relu([A|H] @ W'' + b) ----------------
// Per wave: 32 rows (2 m-tiles), N=128 (8 n-tiles), K=512 (16 k-tiles of 32).
template <int OUT_SPLIT>
__global__ __launch_bounds__(256, 2) void gemm_k(
    const unsigned short* __restrict__ Ahi, const unsigned short* __restrict__ Alo,
    const unsigned short* __restrict__ Hhi, const unsigned short* __restrict__ Hlo,
    const unsigned short* __restrict__ Bp, const float* __restrict__ bias,
    unsigned short* __restrict__ Ohi, unsigned short* __restrict__ Olo,
    float* __restrict__ Of32) {
  const int t = threadIdx.x;
  const int lane = t & 63;
  const int w = blockIdx.x * 4 + (t >> 6);
  const int rbase = w * 32;
  if (rbase >= N_NODES) return;
  const int lm = lane & 15, lk = lane >> 4;
  const int r0c = min(rbase + lm, N_NODES - 1);
  const int r1c = min(rbase + 16 + lm, N_NODES - 1);
  const int koff = lk << 3;

  f32x4 acc[2][8] = {};

#pragma unroll
  for (int p = 0; p < 4; ++p) {
    const unsigned short* pl = (p == 0) ? Ahi : (p == 1) ? Alo
                               : (p == 2) ? Hhi : Hlo;
#pragma unroll
    for (int k2 = 0; k2 < 4; ++k2) {
      const int kt = p * 4 + k2;
      const int kc = (k2 << 5) + koff;
      const bf16x8 a0 = *reinterpret_cast<const bf16x8*>(pl + (size_t)r0c * DIM + kc);
      const bf16x8 a1 = *reinterpret_cast<const bf16x8*>(pl + (size_t)r1c * DIM + kc);
      const unsigned short* bp = Bp + (((size_t)kt * 8) * 64 + lane) * 8;
#pragma unroll
      for (int nt = 0; nt < 8; ++nt) {
        const bf16x8 b = *reinterpret_cast<const bf16x8*>(bp + nt * 64 * 8);
        acc[0][nt] = __builtin_amdgcn_mfma_f32_16x16x32_bf16(a0, b, acc[0][nt], 0, 0, 0);
        acc[1][nt] = __builtin_amdgcn_mfma_f32_16x16x32_bf16(a1, b, acc[1][nt], 0, 0, 0);
      }
    }
  }

#pragma unroll
  for (int nt = 0; nt < 8; ++nt) {
    const int cidx = nt * 16 + lm;
    const float bv = bias[cidx];
#pragma unroll
    for (int mt = 0; mt < 2; ++mt) {
#pragma unroll
      for (int i = 0; i < 4; ++i) {
        const int r = rbase + mt * 16 + lk * 4 + i;
        if (r < N_NODES) {
          float v = acc[mt][nt][i] + bv;
          v = fmaxf(v, 0.0f);
          if (OUT_SPLIT) {
            const unsigned short h = f32_to_bf16_rn(v);
            const unsigned short lw = f32_to_bf16_rn(v - bf16_to_f32(h));
            Ohi[(size_t)r * DIM + cidx] = h;
            Olo[(size_t)r * DIM + cidx] = lw;
          } else {
            Of32[(size_t)r * DIM + cidx] = v;
          }
        }
      }
    }
  }
}

// ---------------- launcher ----------------
extern "C" void kernel_launch(void* const* d_in, const int* in_sizes, int n_in,
                              void* d_out, int out_size, void* d_ws,
                              size_t ws_size, hipStream_t stream) {
  const float* x = (const float*)d_in[0];
  const int* ei = (const int*)d_in[1];
  const float* Wl0 = (const float*)d_in[2];
  const float* bl0 = (const float*)d_in[3];
  const float* Wr0 = (const float*)d_in[4];
  const float* Wl1 = (const float*)d_in[5];
  const float* bl1 = (const float*)d_in[6];
  const float* Wr1 = (const float*)d_in[7];
  float* out = (float*)d_out;
  const int* src = ei;
  const int* dst = ei + N_EDGES;

  char* p = (char*)d_ws;
  auto alloc = [&](size_t bytes) {
    char* q = p;
    p += (bytes + 255) & ~(size_t)255;
    return q;
  };
  int* deg = (int*)alloc((size_t)N_NODES * 4);
  int* rowptr = (int*)alloc((size_t)(N_NODES + 1) * 4);
  int* head = (int*)alloc((size_t)N_NODES * 4);  // doubles as incl-scan temp
  int* col = (int*)alloc((size_t)N_EDGES * 4);
  int* bsum = (int*)alloc(128 * 4);
  int* boffs = (int*)alloc(128 * 4);
  unsigned short* Bp0 = (unsigned short*)alloc(65536 * 2);
  unsigned short* Bp1 = (unsigned short*)alloc(65536 * 2);
  unsigned short* xhi = (unsigned short*)alloc((size_t)N_NODES * DIM * 2);
  unsigned short* xlo = (unsigned short*)alloc((size_t)N_NODES * DIM * 2);
  unsigned short* mhi = (unsigned short*)alloc((size_t)N_NODES * DIM * 2);
  unsigned short* mlo = (unsigned short*)alloc((size_t)N_NODES * DIM * 2);

  const int nScanB = (N_NODES + 1023) / 1024;  // 98

  hipMemsetAsync(deg, 0, (size_t)N_NODES * 4, stream);
  split_k<<<(N_NODES * DIM / 4) / 256, 256, 0, stream>>>(x, xhi, xlo);
  pack_w_k<<<256, 256, 0, stream>>>(Wl0, Wr0, Bp0);
  pack_w_k<<<256, 256, 0, stream>>>(Wl1, Wr1, Bp1);
  hist_k<<<(N_EDGES + 255) / 256, 256, 0, stream>>>(dst, deg);
  scan1_k<<<nScanB, 1024, 0, stream>>>(deg, head, bsum);
  scan2_k<<<1, 128, 0, stream>>>(bsum, boffs, nScanB);
  scan3_k<<<nScanB, 1024, 0, stream>>>(deg, head, boffs, rowptr, head);
  fill_k<<<(N_EDGES + 255) / 256, 256, 0, stream>>>(src, dst, head, col);

  const int gemmBlocks = (((N_NODES + 31) / 32) + 3) / 4;  // 782

  // layer 0: mean(x) planes -> mhi/mlo; gemm writes h1 in-place over mhi/mlo
  agg_k<<<N_NODES / 8, 256, 0, stream>>>(xhi, xlo, rowptr, col, mhi, mlo);
  gemm_k<1><<<gemmBlocks, 256, 0, stream>>>(mhi, mlo, xhi, xlo, Bp0, bl0,
                                            mhi, mlo, nullptr);
  // layer 1: aggregate h1 (now in mhi/mlo) into xhi/xlo; final gemm -> f32 out
  agg_k<<<N_NODES / 8, 256, 0, stream>>>(mhi, mlo, rowptr, col, xhi, xlo);
  gemm_k<0><<<gemmBlocks, 256, 0, stream>>>(xhi, xlo, mhi, mlo, Bp1, bl1,
                                            nullptr, nullptr, out);
}

// Round 3
// 282.516 us; speedup vs baseline: 1.8303x; 1.0992x over previous
//
#include <hip/hip_runtime.h>

#define N_NODES 100000
#define N_EDGES 600000
#define DIM 128

typedef __attribute__((ext_vector_type(8))) short bf16x8;
typedef __attribute__((ext_vector_type(4))) float f32x4;

typedef __attribute__((address_space(1))) const unsigned int g_u32;
typedef __attribute__((address_space(3))) unsigned int l_u32;
__device__ __forceinline__ void stage16(const void* g, void* l) {
  __builtin_amdgcn_global_load_lds((g_u32*)g, (l_u32*)l, 16, 0, 0);
}

__device__ inline unsigned short f32_to_bf16_rn(float f) {
  unsigned int u = __builtin_bit_cast(unsigned int, f);
  unsigned int r = (u + 0x7FFFu + ((u >> 16) & 1u)) >> 16;
  return (unsigned short)r;
}
__device__ inline float bf16_to_f32(unsigned short h) {
  return __builtin_bit_cast(float, (unsigned int)h << 16);
}

// ---------------- split f32 -> (hi, lo) bf16 planes ----------------
__global__ __launch_bounds__(256) void split_k(const float* __restrict__ in,
                                               unsigned short* __restrict__ hi,
                                               unsigned short* __restrict__ lo) {
  const int i = blockIdx.x * 256 + threadIdx.x;  // one float4 per thread
  const float4 v = reinterpret_cast<const float4*>(in)[i];
  const float f[4] = {v.x, v.y, v.z, v.w};
  unsigned short h[4], l[4];
#pragma unroll
  for (int j = 0; j < 4; ++j) {
    h[j] = f32_to_bf16_rn(f[j]);
    l[j] = f32_to_bf16_rn(f[j] - bf16_to_f32(h[j]));
  }
  uint2 hp, lp;
  hp.x = (unsigned)h[0] | ((unsigned)h[1] << 16);
  hp.y = (unsigned)h[2] | ((unsigned)h[3] << 16);
  lp.x = (unsigned)l[0] | ((unsigned)l[1] << 16);
  lp.y = (unsigned)l[2] | ((unsigned)l[3] << 16);
  reinterpret_cast<uint2*>(hi)[i] = hp;
  reinterpret_cast<uint2*>(lo)[i] = lp;
}

// ---------------- pack weights into MFMA fragment order ----------------
// B'' rows 0-127: Wl_hi, 128-255: Wl_lo, 256-383: Wr_hi, 384-511: Wr_lo
// packed[(((kt*8+nt)*64)+lane)*8 + j] = B''[kt*32 + (lane>>4)*8 + j][nt*16 + (lane&15)]
__global__ __launch_bounds__(256) void pack_w_k(const float* __restrict__ Wl,
                                                const float* __restrict__ Wr,
                                                unsigned short* __restrict__ packed) {
  const int idx = blockIdx.x * 256 + threadIdx.x;  // 0..65535
  const int j = idx & 7;
  const int l = (idx >> 3) & 63;
  const int nt = (idx >> 9) & 7;
  const int kt = idx >> 12;
  const int kk = kt * 32 + ((l >> 4) << 3) + j;
  const int n = nt * 16 + (l & 15);
  const int p = kk >> 7;            // 0:Wl_hi 1:Wl_lo 2:Wr_hi 3:Wr_lo
  const int k = kk & 127;
  const float w = ((p < 2) ? Wl : Wr)[k * 128 + n];
  const unsigned short h = f32_to_bf16_rn(w);
  const unsigned short out =
      (p & 1) ? f32_to_bf16_rn(w - bf16_to_f32(h)) : h;
  packed[idx] = out;
}

// ---------------- CSR build ----------------
__global__ void hist_k(const int* __restrict__ dst, int* __restrict__ deg) {
  int e = blockIdx.x * blockDim.x + threadIdx.x;
  if (e < N_EDGES) atomicAdd(&deg[dst[e]], 1);
}

__global__ __launch_bounds__(1024) void scan1_k(const int* __restrict__ deg,
                                                int* __restrict__ incl,
                                                int* __restrict__ bsum) {
  __shared__ int wsum[16];
  const int t = threadIdx.x, lane = t & 63, w = t >> 6;
  const int gi = blockIdx.x * 1024 + t;
  int v = (gi < N_NODES) ? deg[gi] : 0;
  int s = v;
#pragma unroll
  for (int off = 1; off < 64; off <<= 1) {
    int u = __shfl_up(s, off);
    if (lane >= off) s += u;
  }
  if (lane == 63) wsum[w] = s;
  __syncthreads();
  if (t < 16) {
    int ws = wsum[t];
#pragma unroll
    for (int off = 1; off < 16; off <<= 1) {
      int u = __shfl_up(ws, off);
      if (t >= off) ws += u;
    }
    wsum[t] = ws;
  }
  __syncthreads();
  const int val = s + (w ? wsum[w - 1] : 0);
  if (gi < N_NODES) incl[gi] = val;
  if (t == 1023) bsum[blockIdx.x] = val;
}

__global__ void scan2_k(const int* __restrict__ bsum, int* __restrict__ boffs,
                        int nb) {
  __shared__ int w0;
  const int t = threadIdx.x;  // 128 threads
  int v = (t < nb) ? bsum[t] : 0;
  int s = v;
#pragma unroll
  for (int off = 1; off < 64; off <<= 1) {
    int u = __shfl_up(s, off);
    if ((t & 63) >= off) s += u;
  }
  if (t == 63) w0 = s;
  __syncthreads();
  const int excl = s - v + ((t >> 6) ? w0 : 0);
  if (t < nb) boffs[t] = excl;
}

__global__ __launch_bounds__(1024) void scan3_k(const int* __restrict__ deg,
                                                const int* __restrict__ incl,
                                                const int* __restrict__ boffs,
                                                int* __restrict__ rowptr,
                                                int* __restrict__ head) {
  const int gi = blockIdx.x * 1024 + threadIdx.x;
  if (gi < N_NODES) {
    const int e = incl[gi] - deg[gi] + boffs[blockIdx.x];
    rowptr[gi] = e;
    head[gi] = e;
  }
  if (gi == 0) rowptr[N_NODES] = N_EDGES;
}

__global__ void fill_k(const int* __restrict__ src, const int* __restrict__ dst,
                       int* __restrict__ head, int* __restrict__ col) {
  int e = blockIdx.x * blockDim.x + threadIdx.x;
  if (e < N_EDGES) {
    int p = atomicAdd(&head[dst[e]], 1);
    col[p] = src[e];
  }
}

// ---------------- mean aggregation over split planes ----------------
__global__ __launch_bounds__(256) void agg_k(
    const unsigned short* __restrict__ hi, const unsigned short* __restrict__ lo,
    const int* __restrict__ rowptr, const int* __restrict__ col,
    unsigned short* __restrict__ mhi, unsigned short* __restrict__ mlo) {
  const int t = threadIdx.x;
  const int node = blockIdx.x * 8 + (t >> 5);
  const int c = t & 31;
  const unsigned short* plane = (c & 16) ? lo : hi;
  const int off = (c & 15) << 3;  // 8 bf16 per lane
  const int beg = rowptr[node], end = rowptr[node + 1];
  float acc[8] = {};
  for (int i = beg; i < end; ++i) {
    const uint4 v = *reinterpret_cast<const uint4*>(
        plane + (size_t)col[i] * DIM + off);
    const unsigned int u[4] = {v.x, v.y, v.z, v.w};
#pragma unroll
    for (int q = 0; q < 4; ++q) {
      acc[2 * q] += __builtin_bit_cast(float, u[q] << 16);
      acc[2 * q + 1] += __builtin_bit_cast(float, u[q] & 0xFFFF0000u);
    }
  }
  const int d = end - beg;
  const float inv = 1.0f / (float)(d > 1 ? d : 1);
  unsigned short outv[8];
#pragma unroll
  for (int j = 0; j < 8; ++j) {
    const float tot = acc[j] + __shfl_xor(acc[j], 16);
    const float m = tot * inv;
    const unsigned short h = f32_to_bf16_rn(m);
    const unsigned short lw = f32_to_bf16_rn(m - bf16_to_f32(h));
    outv[j] = (c & 16) ? lw : h;
  }
  uint4 pk;
  pk.x = (unsigned)outv[0] | ((unsigned)outv[1] << 16);
  pk.y = (unsigned)outv[2] | ((unsigned)outv[3] << 16);
  pk.z = (unsigned)outv[4] | ((unsigned)outv[5] << 16);
  pk.w = (unsigned)outv[6] | ((unsigned)outv[7] << 16);
  unsigned short* op = (c & 16) ? mlo : mhi;
  *reinterpret_cast<uint4*>(op + (size_t)node * DIM + off) = pk;
}

// ---------------- MFMA GEMM: out = relu([A|H] @ W'' + b) ----------------
// Block: 256 thr / 4 waves / 128 rows. Wave: 32 rows (2 m-tiles) x N=128.
// K=512 as 16 k-tiles of 32. B staged in LDS (8 KB/kt, double-buffered via
// global_load_lds); A fragments register-prefetched one kt ahead.
template <int OUT_SPLIT>
__global__ __launch_bounds__(256, 3) void gemm_k(
    const unsigned short* __restrict__ Ahi, const unsigned short* __restrict__ Alo,
    const unsigned short* __restrict__ Hhi, const unsigned short* __restrict__ Hlo,
    const unsigned short* __restrict__ Bp, const float* __restrict__ bias,
    unsigned short* __restrict__ Ohi, unsigned short* __restrict__ Olo,
    float* __restrict__ Of32) {
  __shared__ unsigned short Bl[2][4096];  // 8 KB per buffer
  const int t = threadIdx.x;
  const int lane = t & 63;
  const int wid = t >> 6;
  const int rbase = blockIdx.x * 128 + wid * 32;
  const int lm = lane & 15, lk = lane >> 4;
  const int r0 = min(rbase + lm, N_NODES - 1);
  const int r1 = min(rbase + 16 + lm, N_NODES - 1);
  const unsigned short* planes[4] = {Ahi, Alo, Hhi, Hlo};

  f32x4 acc[2][8] = {};

  // prologue: stage kt=0, prefetch A(kt=0)
  {
    const unsigned short* gb = Bp;
#pragma unroll
    for (int s = 0; s < 2; ++s) {
      const int seg = wid * 2 + s;
      stage16(gb + seg * 512 + lane * 8, &Bl[0][seg * 512]);
    }
  }
  bf16x8 aN0, aN1;
  {
    const int kc = lk << 3;
    aN0 = *reinterpret_cast<const bf16x8*>(Ahi + (size_t)r0 * DIM + kc);
    aN1 = *reinterpret_cast<const bf16x8*>(Ahi + (size_t)r1 * DIM + kc);
  }
  __syncthreads();

#pragma unroll
  for (int kt = 0; kt < 16; ++kt) {
    const int buf = kt & 1;
    if (kt < 15) {  // stage next B chunk
      const unsigned short* gb = Bp + (kt + 1) * 4096;
#pragma unroll
      for (int s = 0; s < 2; ++s) {
        const int seg = wid * 2 + s;
        stage16(gb + seg * 512 + lane * 8, &Bl[buf ^ 1][seg * 512]);
      }
    }
    const bf16x8 aC0 = aN0, aC1 = aN1;
    if (kt < 15) {  // prefetch next A fragments
      const unsigned short* pl = planes[(kt + 1) >> 2];
      const int kc = (((kt + 1) & 3) << 5) + (lk << 3);
      aN0 = *reinterpret_cast<const bf16x8*>(pl + (size_t)r0 * DIM + kc);
      aN1 = *reinterpret_cast<const bf16x8*>(pl + (size_t)r1 * DIM + kc);
    }
#pragma unroll
    for (int nt = 0; nt < 8; ++nt) {
      const bf16x8 b =
          *reinterpret_cast<const bf16x8*>(&Bl[buf][(nt * 64 + lane) * 8]);
      acc[0][nt] = __builtin_amdgcn_mfma_f32_16x16x32_bf16(aC0, b, acc[0][nt], 0, 0, 0);
      acc[1][nt] = __builtin_amdgcn_mfma_f32_16x16x32_bf16(aC1, b, acc[1][nt], 0, 0, 0);
    }
    __syncthreads();
  }

#pragma unroll
  for (int nt = 0; nt < 8; ++nt) {
    const int cidx = nt * 16 + lm;
    const float bv = bias[cidx];
#pragma unroll
    for (int mt = 0; mt < 2; ++mt) {
#pragma unroll
      for (int i = 0; i < 4; ++i) {
        const int r = rbase + mt * 16 + lk * 4 + i;
        if (r < N_NODES) {
          float v = acc[mt][nt][i] + bv;
          v = fmaxf(v, 0.0f);
          if (OUT_SPLIT) {
            const unsigned short h = f32_to_bf16_rn(v);
            const unsigned short lw = f32_to_bf16_rn(v - bf16_to_f32(h));
            Ohi[(size_t)r * DIM + cidx] = h;
            Olo[(size_t)r * DIM + cidx] = lw;
          } else {
            Of32[(size_t)r * DIM + cidx] = v;
          }
        }
      }
    }
  }
}

// ---------------- launcher ----------------
extern "C" void kernel_launch(void* const* d_in, const int* in_sizes, int n_in,
                              void* d_out, int out_size, void* d_ws,
                              size_t ws_size, hipStream_t stream) {
  const float* x = (const float*)d_in[0];
  const int* ei = (const int*)d_in[1];
  const float* Wl0 = (const float*)d_in[2];
  const float* bl0 = (const float*)d_in[3];
  const float* Wr0 = (const float*)d_in[4];
  const float* Wl1 = (const float*)d_in[5];
  const float* bl1 = (const float*)d_in[6];
  const float* Wr1 = (const float*)d_in[7];
  float* out = (float*)d_out;
  const int* src = ei;
  const int* dst = ei + N_EDGES;

  char* p = (char*)d_ws;
  auto alloc = [&](size_t bytes) {
    char* q = p;
    p += (bytes + 255) & ~(size_t)255;
    return q;
  };
  int* deg = (int*)alloc((size_t)N_NODES * 4);
  int* rowptr = (int*)alloc((size_t)(N_NODES + 1) * 4);
  int* head = (int*)alloc((size_t)N_NODES * 4);  // doubles as incl-scan temp
  int* col = (int*)alloc((size_t)N_EDGES * 4);
  int* bsum = (int*)alloc(128 * 4);
  int* boffs = (int*)alloc(128 * 4);
  unsigned short* Bp0 = (unsigned short*)alloc(65536 * 2);
  unsigned short* Bp1 = (unsigned short*)alloc(65536 * 2);
  unsigned short* xhi = (unsigned short*)alloc((size_t)N_NODES * DIM * 2);
  unsigned short* xlo = (unsigned short*)alloc((size_t)N_NODES * DIM * 2);
  unsigned short* mhi = (unsigned short*)alloc((size_t)N_NODES * DIM * 2);
  unsigned short* mlo = (unsigned short*)alloc((size_t)N_NODES * DIM * 2);

  const int nScanB = (N_NODES + 1023) / 1024;  // 98

  hipMemsetAsync(deg, 0, (size_t)N_NODES * 4, stream);
  split_k<<<(N_NODES * DIM / 4) / 256, 256, 0, stream>>>(x, xhi, xlo);
  pack_w_k<<<256, 256, 0, stream>>>(Wl0, Wr0, Bp0);
  pack_w_k<<<256, 256, 0, stream>>>(Wl1, Wr1, Bp1);
  hist_k<<<(N_EDGES + 255) / 256, 256, 0, stream>>>(dst, deg);
  scan1_k<<<nScanB, 1024, 0, stream>>>(deg, head, bsum);
  scan2_k<<<1, 128, 0, stream>>>(bsum, boffs, nScanB);
  scan3_k<<<nScanB, 1024, 0, stream>>>(deg, head, boffs, rowptr, head);
  fill_k<<<(N_EDGES + 255) / 256, 256, 0, stream>>>(src, dst, head, col);

  const int gemmBlocks = (N_NODES + 127) / 128;  // 782

  // layer 0: mean(x) planes -> mhi/mlo; gemm writes h1 in-place over mhi/mlo
  agg_k<<<N_NODES / 8, 256, 0, stream>>>(xhi, xlo, rowptr, col, mhi, mlo);
  gemm_k<1><<<gemmBlocks, 256, 0, stream>>>(mhi, mlo, xhi, xlo, Bp0, bl0,
                                            mhi, mlo, nullptr);
  // layer 1: aggregate h1 (now in mhi/mlo) into xhi/xlo; final gemm -> f32 out
  agg_k<<<N_NODES / 8, 256, 0, stream>>>(mhi, mlo, rowptr, col, xhi, xlo);
  gemm_k<0><<<gemmBlocks, 256, 0, stream>>>(xhi, xlo, mhi, mlo, Bp1, bl1,
                                            nullptr, nullptr, out);
}

// Round 4
// 255.602 us; speedup vs baseline: 2.0230x; 1.1053x over previous
//
#include <hip/hip_runtime.h>

#define N_NODES 100000
#define N_EDGES 600000
#define DIM 128

typedef __attribute__((ext_vector_type(8))) short bf16x8;
typedef __attribute__((ext_vector_type(4))) float f32x4;

typedef __attribute__((address_space(1))) const unsigned int g_u32;
typedef __attribute__((address_space(3))) unsigned int l_u32;
__device__ __forceinline__ void stage16(const void* g, void* l) {
  __builtin_amdgcn_global_load_lds((g_u32*)g, (l_u32*)l, 16, 0, 0);
}

__device__ __forceinline__ unsigned short f32_to_bf16_rn(float f) {
  unsigned int u = __builtin_bit_cast(unsigned int, f);
  unsigned int r = (u + 0x7FFFu + ((u >> 16) & 1u)) >> 16;
  return (unsigned short)r;
}
__device__ __forceinline__ float bf16_to_f32(unsigned short h) {
  return __builtin_bit_cast(float, (unsigned int)h << 16);
}

// pack one f32 into u32 = (hi_bf16 << 16) | lo_bf16, hi=rn(v), lo=rn(v-hi)
__device__ __forceinline__ unsigned int pack_hl(float v) {
  const unsigned int u = __builtin_bit_cast(unsigned int, v);
  const unsigned int r1 = u + 0x7FFFu + ((u >> 16) & 1u);
  const unsigned int hb = r1 & 0xFFFF0000u;  // bf(hi) bits
  const float fl = v - __builtin_bit_cast(float, hb);
  const unsigned int u2 = __builtin_bit_cast(unsigned int, fl);
  const unsigned int r2 = (u2 + 0x7FFFu + ((u2 >> 16) & 1u)) >> 16;
  return hb | (r2 & 0xFFFFu);
}

// ---------------- pack weights into MFMA fragment order ----------------
// g-tile sequence (4096 shorts each): [Wl_hi k0-31, Wl_lo k0-31, Wl_hi k32-63,
// Wl_lo k32-63, ... , Wr_hi k0-31, Wr_lo k0-31, ...]
// packed[((g*8+nt)*64+l)*8+j] = plane[(g>>1)&3 k-tile][(l>>4)*8+j][nt*16+(l&15)]
__global__ __launch_bounds__(256) void pack_w_k(const float* __restrict__ Wl,
                                                const float* __restrict__ Wr,
                                                unsigned short* __restrict__ packed) {
  const int idx = blockIdx.x * 256 + threadIdx.x;  // 0..65535
  const int j = idx & 7;
  const int l = (idx >> 3) & 63;
  const int nt = (idx >> 9) & 7;
  const int g = idx >> 12;
  const int k = (((g >> 1) & 3) << 5) + ((l >> 4) << 3) + j;
  const int n = (nt << 4) + (l & 15);
  const float w = ((g < 8) ? Wl : Wr)[k * 128 + n];
  const unsigned short h = f32_to_bf16_rn(w);
  packed[idx] = (g & 1) ? f32_to_bf16_rn(w - bf16_to_f32(h)) : h;
}

// ---------------- CSR build ----------------
__global__ void hist_k(const int* __restrict__ dst, int* __restrict__ deg) {
  int e = blockIdx.x * blockDim.x + threadIdx.x;
  if (e < N_EDGES) atomicAdd(&deg[dst[e]], 1);
}

__global__ __launch_bounds__(1024) void scan1_k(const int* __restrict__ deg,
                                                int* __restrict__ incl,
                                                int* __restrict__ bsum) {
  __shared__ int wsum[16];
  const int t = threadIdx.x, lane = t & 63, w = t >> 6;
  const int gi = blockIdx.x * 1024 + t;
  int v = (gi < N_NODES) ? deg[gi] : 0;
  int s = v;
#pragma unroll
  for (int off = 1; off < 64; off <<= 1) {
    int u = __shfl_up(s, off);
    if (lane >= off) s += u;
  }
  if (lane == 63) wsum[w] = s;
  __syncthreads();
  if (t < 16) {
    int ws = wsum[t];
#pragma unroll
    for (int off = 1; off < 16; off <<= 1) {
      int u = __shfl_up(ws, off);
      if (t >= off) ws += u;
    }
    wsum[t] = ws;
  }
  __syncthreads();
  const int val = s + (w ? wsum[w - 1] : 0);
  if (gi < N_NODES) incl[gi] = val;
  if (t == 1023) bsum[blockIdx.x] = val;
}

__global__ void scan2_k(const int* __restrict__ bsum, int* __restrict__ boffs,
                        int nb) {
  __shared__ int w0;
  const int t = threadIdx.x;  // 128 threads
  int v = (t < nb) ? bsum[t] : 0;
  int s = v;
#pragma unroll
  for (int off = 1; off < 64; off <<= 1) {
    int u = __shfl_up(s, off);
    if ((t & 63) >= off) s += u;
  }
  if (t == 63) w0 = s;
  __syncthreads();
  const int excl = s - v + ((t >> 6) ? w0 : 0);
  if (t < nb) boffs[t] = excl;
}

__global__ __launch_bounds__(1024) void scan3_k(const int* __restrict__ deg,
                                                const int* __restrict__ incl,
                                                const int* __restrict__ boffs,
                                                int* __restrict__ rowptr,
                                                int* __restrict__ head) {
  const int gi = blockIdx.x * 1024 + threadIdx.x;
  if (gi < N_NODES) {
    const int e = incl[gi] - deg[gi] + boffs[blockIdx.x];
    rowptr[gi] = e;
    head[gi] = e;
  }
  if (gi == 0) rowptr[N_NODES] = N_EDGES;
}

__global__ void fill_k(const int* __restrict__ src, const int* __restrict__ dst,
                       int* __restrict__ head, int* __restrict__ col) {
  int e = blockIdx.x * blockDim.x + threadIdx.x;
  if (e < N_EDGES) {
    int p = atomicAdd(&head[dst[e]], 1);
    col[p] = src[e];
  }
}

// ---------------- mean aggregation: gather one u32 plane ----------------
// PACKED=0: plane holds f32 bits (layer 0: x). PACKED=1: plane holds
// (hi<<16|lo) bf16 pairs (layer 1: h1). Output: packed mean plane.
// 8 nodes / 256-thread block; 32 lanes per node (uint4 = 4 dims per lane).
// Depth-4 neighbor pipeline: 4 independent gathers in flight.
template <int PACKED>
__global__ __launch_bounds__(256) void agg_k(
    const unsigned int* __restrict__ plane, const int* __restrict__ rowptr,
    const int* __restrict__ col, unsigned int* __restrict__ meanp) {
  const int t = threadIdx.x;
  const int node = blockIdx.x * 8 + (t >> 5);
  const int q = t & 31;  // uint4 index within the 128-dim row
  const int beg = rowptr[node], end = rowptr[node + 1];
  const uint4* P = reinterpret_cast<const uint4*>(plane);
  float a0 = 0.f, a1 = 0.f, a2 = 0.f, a3 = 0.f;

  auto accum = [&](uint4 v) {
    if (PACKED) {
      a0 += __builtin_bit_cast(float, v.x & 0xFFFF0000u);
      a0 += __builtin_bit_cast(float, v.x << 16);
      a1 += __builtin_bit_cast(float, v.y & 0xFFFF0000u);
      a1 += __builtin_bit_cast(float, v.y << 16);
      a2 += __builtin_bit_cast(float, v.z & 0xFFFF0000u);
      a2 += __builtin_bit_cast(float, v.z << 16);
      a3 += __builtin_bit_cast(float, v.w & 0xFFFF0000u);
      a3 += __builtin_bit_cast(float, v.w << 16);
    } else {
      a0 += __builtin_bit_cast(float, v.x);
      a1 += __builtin_bit_cast(float, v.y);
      a2 += __builtin_bit_cast(float, v.z);
      a3 += __builtin_bit_cast(float, v.w);
    }
  };

  for (int i = beg; i < end; i += 4) {
    const int i1 = min(i + 1, end - 1);
    const int i2 = min(i + 2, end - 1);
    const int i3 = min(i + 3, end - 1);
    const int c0 = col[i], c1 = col[i1], c2 = col[i2], c3 = col[i3];
    const uint4 v0 = P[(size_t)c0 * 32 + q];
    const uint4 v1 = P[(size_t)c1 * 32 + q];
    const uint4 v2 = P[(size_t)c2 * 32 + q];
    const uint4 v3 = P[(size_t)c3 * 32 + q];
    accum(v0);
    if (i + 1 < end) accum(v1);
    if (i + 2 < end) accum(v2);
    if (i + 3 < end) accum(v3);
  }

  const int d = end - beg;
  const float inv = 1.0f / (float)(d > 1 ? d : 1);
  uint4 w;
  w.x = pack_hl(a0 * inv);
  w.y = pack_hl(a1 * inv);
  w.z = pack_hl(a2 * inv);
  w.w = pack_hl(a3 * inv);
  reinterpret_cast<uint4*>(meanp)[(size_t)node * 32 + q] = w;
}

// ---------------- fragment unpack helpers ----------------
__device__ __forceinline__ void unpack_pk(uint4 p0, uint4 p1, bf16x8& hi,
                                          bf16x8& lo) {
  const unsigned int u[8] = {p0.x, p0.y, p0.z, p0.w, p1.x, p1.y, p1.z, p1.w};
  uint4 hw, lw;
  unsigned int* hp = &hw.x;
  unsigned int* lp = &lw.x;
#pragma unroll
  for (int w = 0; w < 4; ++w) {
    hp[w] = __builtin_amdgcn_perm(u[2 * w + 1], u[2 * w], 0x07060302u);
    lp[w] = __builtin_amdgcn_perm(u[2 * w + 1], u[2 * w], 0x05040100u);
  }
  hi = __builtin_bit_cast(bf16x8, hw);
  lo = __builtin_bit_cast(bf16x8, lw);
}

__device__ __forceinline__ void split_f32(uint4 p0, uint4 p1, bf16x8& hi,
                                          bf16x8& lo) {
  const unsigned int u[8] = {p0.x, p0.y, p0.z, p0.w, p1.x, p1.y, p1.z, p1.w};
  unsigned int hb[8], l16[8];
#pragma unroll
  for (int e = 0; e < 8; ++e) {
    const unsigned int r1 = u[e] + 0x7FFFu + ((u[e] >> 16) & 1u);
    hb[e] = r1 & 0xFFFF0000u;
    const float fl = __builtin_bit_cast(float, u[e]) -
                     __builtin_bit_cast(float, hb[e]);
    const unsigned int u2 = __builtin_bit_cast(unsigned int, fl);
    l16[e] = (u2 + 0x7FFFu + ((u2 >> 16) & 1u)) >> 16;
  }
  uint4 hw, lw;
  unsigned int* hp = &hw.x;
  unsigned int* lp = &lw.x;
#pragma unroll
  for (int w = 0; w < 4; ++w) {
    hp[w] = (hb[2 * w] >> 16) | (hb[2 * w + 1] & 0xFFFF0000u);
    lp[w] = (l16[2 * w] & 0xFFFFu) | (l16[2 * w + 1] << 16);
  }
  hi = __builtin_bit_cast(bf16x8, hw);
  lo = __builtin_bit_cast(bf16x8, lw);
}

// ---------------- MFMA GEMM: out = relu(mean@Wl + b + h@Wr) ----------------
// Block: 256 thr / 4 waves / 128 rows; wave = 32 rows (2 m-tiles) x N=128.
// 8 super-steps: ss 0-3 A-operand (packed mean) x Wl hi/lo tile pair;
// ss 4-7 H-operand (packed h or f32 x) x Wr pair. Per ss per row one 32 B
// load gives both hi and lo fragments; B pair (16 KB) staged in LDS,
// double-buffered via global_load_lds; 32 MFMA per ss.
template <int HF32, int OUTF32>
__global__ __launch_bounds__(256, 3) void gemm_k(
    const unsigned int* __restrict__ Ap, const unsigned int* __restrict__ Hp,
    const unsigned short* __restrict__ Bp, const float* __restrict__ bias,
    unsigned int* __restrict__ Op, float* __restrict__ Of) {
  __shared__ unsigned short Bl[2][8192];  // 16 KB per buffer
  const int t = threadIdx.x;
  const int lane = t & 63;
  const int wid = t >> 6;
  const int rbase = blockIdx.x * 128 + wid * 32;
  const int lm = lane & 15, lk = lane >> 4;
  const size_t r0 = (size_t)min(rbase + lm, N_NODES - 1);
  const size_t r1 = (size_t)min(rbase + 16 + lm, N_NODES - 1);
  const uint4* PA = reinterpret_cast<const uint4*>(Ap);
  const uint4* PH = reinterpret_cast<const uint4*>(Hp);

  f32x4 acc[2][8] = {};

  auto stageB = [&](int ss, int nb) {
#pragma unroll
    for (int c = 0; c < 4; ++c) {
      const int e = (c * 256 + t) * 8;
      stage16(Bp + ss * 8192 + e, &Bl[nb][e]);
    }
  };

  uint4 c00, c01, c10, c11, n00, n01, n10, n11;
  stageB(0, 0);
  {
    const int kb = lk * 2;
    c00 = PA[r0 * 32 + kb];
    c01 = PA[r0 * 32 + kb + 1];
    c10 = PA[r1 * 32 + kb];
    c11 = PA[r1 * 32 + kb + 1];
  }
  __syncthreads();

#pragma unroll
  for (int ss = 0; ss < 8; ++ss) {
    const int buf = ss & 1;
    if (ss < 7) stageB(ss + 1, buf ^ 1);

    bf16x8 fh0, fl0, fh1, fl1;
    if (HF32 && ss >= 4) {
      split_f32(c00, c01, fh0, fl0);
      split_f32(c10, c11, fh1, fl1);
    } else {
      unpack_pk(c00, c01, fh0, fl0);
      unpack_pk(c10, c11, fh1, fl1);
    }

    if (ss < 7) {
      const uint4* P = (ss + 1 < 4) ? PA : PH;
      const int kb = (((ss + 1) & 3) << 3) + lk * 2;
      n00 = P[r0 * 32 + kb];
      n01 = P[r0 * 32 + kb + 1];
      n10 = P[r1 * 32 + kb];
      n11 = P[r1 * 32 + kb + 1];
    }

#pragma unroll
    for (int nt = 0; nt < 8; ++nt) {
      const bf16x8 bh =
          *reinterpret_cast<const bf16x8*>(&Bl[buf][(nt * 64 + lane) * 8]);
      acc[0][nt] = __builtin_amdgcn_mfma_f32_16x16x32_bf16(fh0, bh, acc[0][nt], 0, 0, 0);
      acc[1][nt] = __builtin_amdgcn_mfma_f32_16x16x32_bf16(fh1, bh, acc[1][nt], 0, 0, 0);
      const bf16x8 bl = *reinterpret_cast<const bf16x8*>(
          &Bl[buf][4096 + (nt * 64 + lane) * 8]);
      acc[0][nt] = __builtin_amdgcn_mfma_f32_16x16x32_bf16(fl0, bl, acc[0][nt], 0, 0, 0);
      acc[1][nt] = __builtin_amdgcn_mfma_f32_16x16x32_bf16(fl1, bl, acc[1][nt], 0, 0, 0);
    }
    __syncthreads();
    c00 = n00;
    c01 = n01;
    c10 = n10;
    c11 = n11;
  }

#pragma unroll
  for (int nt = 0; nt < 8; ++nt) {
    const int cidx = nt * 16 + lm;
    const float bv = bias[cidx];
#pragma unroll
    for (int mt = 0; mt < 2; ++mt) {
#pragma unroll
      for (int i = 0; i < 4; ++i) {
        const int r = rbase + mt * 16 + lk * 4 + i;
        if (r < N_NODES) {
          float v = acc[mt][nt][i] + bv;
          v = fmaxf(v, 0.0f);
          if (OUTF32) {
            Of[(size_t)r * DIM + cidx] = v;
          } else {
            Op[(size_t)r * DIM + cidx] = pack_hl(v);
          }
        }
      }
    }
  }
}

// ---------------- launcher ----------------
extern "C" void kernel_launch(void* const* d_in, const int* in_sizes, int n_in,
                              void* d_out, int out_size, void* d_ws,
                              size_t ws_size, hipStream_t stream) {
  const float* x = (const float*)d_in[0];
  const int* ei = (const int*)d_in[1];
  const float* Wl0 = (const float*)d_in[2];
  const float* bl0 = (const float*)d_in[3];
  const float* Wr0 = (const float*)d_in[4];
  const float* Wl1 = (const float*)d_in[5];
  const float* bl1 = (const float*)d_in[6];
  const float* Wr1 = (const float*)d_in[7];
  float* out = (float*)d_out;
  const int* src = ei;
  const int* dst = ei + N_EDGES;

  char* p = (char*)d_ws;
  auto alloc = [&](size_t bytes) {
    char* q = p;
    p += (bytes + 255) & ~(size_t)255;
    return q;
  };
  int* deg = (int*)alloc((size_t)N_NODES * 4);
  int* rowptr = (int*)alloc((size_t)(N_NODES + 1) * 4);
  int* head = (int*)alloc((size_t)N_NODES * 4);  // doubles as incl-scan temp
  int* col = (int*)alloc((size_t)N_EDGES * 4);
  int* bsum = (int*)alloc(128 * 4);
  int* boffs = (int*)alloc(128 * 4);
  unsigned short* Bp0 = (unsigned short*)alloc(65536 * 2);
  unsigned short* Bp1 = (unsigned short*)alloc(65536 * 2);
  unsigned int* meanp = (unsigned int*)alloc((size_t)N_NODES * DIM * 4);
  unsigned int* h1p = (unsigned int*)alloc((size_t)N_NODES * DIM * 4);

  const int nScanB = (N_NODES + 1023) / 1024;  // 98

  hipMemsetAsync(deg, 0, (size_t)N_NODES * 4, stream);
  pack_w_k<<<256, 256, 0, stream>>>(Wl0, Wr0, Bp0);
  pack_w_k<<<256, 256, 0, stream>>>(Wl1, Wr1, Bp1);
  hist_k<<<(N_EDGES + 255) / 256, 256, 0, stream>>>(dst, deg);
  scan1_k<<<nScanB, 1024, 0, stream>>>(deg, head, bsum);
  scan2_k<<<1, 128, 0, stream>>>(bsum, boffs, nScanB);
  scan3_k<<<nScanB, 1024, 0, stream>>>(deg, head, boffs, rowptr, head);
  fill_k<<<(N_EDGES + 255) / 256, 256, 0, stream>>>(src, dst, head, col);

  const int gemmBlocks = (N_NODES + 127) / 128;  // 782

  // layer 0: gather x (f32), write packed mean; gemm0: A=mean, H=x(f32)->h1p
  agg_k<0><<<N_NODES / 8, 256, 0, stream>>>((const unsigned int*)x, rowptr,
                                            col, meanp);
  gemm_k<1, 0><<<gemmBlocks, 256, 0, stream>>>(meanp, (const unsigned int*)x,
                                               Bp0, bl0, h1p, nullptr);
  // layer 1: gather h1p (packed), write packed mean; gemm1 -> f32 out
  agg_k<1><<<N_NODES / 8, 256, 0, stream>>>(h1p, rowptr, col, meanp);
  gemm_k<0, 1><<<gemmBlocks, 256, 0, stream>>>(meanp, h1p, Bp1, bl1, nullptr,
                                               out);
}